// Round 7
// baseline (112.487 us; speedup 1.0000x reference)
//
#include <hip/hip_runtime.h>

#define S_LEN 2048
#define E_DIM 512
#define NTOK  16384   // B*S = 8*2048

typedef __bf16 bf16x8_t __attribute__((ext_vector_type(8)));
typedef float f32x4_t __attribute__((ext_vector_type(4)));
typedef unsigned short u16x8_t __attribute__((ext_vector_type(8)));

__device__ __forceinline__ float bf2f(unsigned short h) {
  return __uint_as_float(((unsigned)h) << 16);
}
// native casts -> compiler emits v_cvt_pk_bf16_f32 (m240: don't hand-roll)
__device__ __forceinline__ u16x8_t cvt8n(float4 a, float4 b) {
  bf16x8_t t;
  t[0] = (__bf16)a.x; t[1] = (__bf16)a.y; t[2] = (__bf16)a.z; t[3] = (__bf16)a.w;
  t[4] = (__bf16)b.x; t[5] = (__bf16)b.y; t[6] = (__bf16)b.z; t[7] = (__bf16)b.w;
  union { bf16x8_t h; u16x8_t u; } cv; cv.h = t; return cv.u;
}
// async global->LDS, 16B per lane; LDS dest = wave-uniform base + lane*16
__device__ __forceinline__ void gload16(const void* g, void* l) {
  __builtin_amdgcn_global_load_lds(
      (const __attribute__((address_space(1))) unsigned int*)g,
      (__attribute__((address_space(3))) unsigned int*)l, 16, 0, 0);
}

// ---------------- prepass: offsets+q->bf16 (blocks 0..4095) | k,v,W,OW ->bf16 ----------------
__global__ __launch_bounds__(256)
void prepass_kernel(const float* __restrict__ q, const float* __restrict__ k,
                    const float* __restrict__ v, const float* __restrict__ ipw,
                    const float* __restrict__ outw, const float* __restrict__ ow,
                    const float* __restrict__ ob, int* __restrict__ idx,
                    unsigned short* __restrict__ Qbf, unsigned short* __restrict__ Kb,
                    unsigned short* __restrict__ Vb, unsigned short* __restrict__ Wb,
                    unsigned short* __restrict__ OWb)
{
  const int bid = blockIdx.x;
  if (bid >= 4096) {
    const float* src; unsigned short* dst; size_t off;
    if (bid < 8192)       { src = k;    dst = Kb;  off = (size_t)(bid - 4096) * 2048; }
    else if (bid < 12288) { src = v;    dst = Vb;  off = (size_t)(bid - 8192) * 2048; }
    else if (bid < 12672) { src = ipw;  dst = Wb;  off = (size_t)(bid - 12288) * 2048; }
    else                  { src = outw; dst = OWb; off = (size_t)(bid - 12672) * 2048; }
    const size_t i = off + (size_t)threadIdx.x * 8;
    const float4 a = *(const float4*)(src + i);
    const float4 b = *(const float4*)(src + i + 4);
    *(u16x8_t*)(dst + i) = cvt8n(a, b);
    return;
  }
  const int wid  = threadIdx.x >> 6;
  const int lane = threadIdx.x & 63;
  const int n = bid * 4 + wid;                 // token
  const int s = n & (S_LEN - 1);
  const float* qr = q + (size_t)n * E_DIM + lane * 8;
  const float4 q0 = *(const float4*)qr;
  const float4 q1 = *(const float4*)(qr + 4);
  *(u16x8_t*)(Qbf + (size_t)n * E_DIM + lane * 8) = cvt8n(q0, q1);
  float myoff = 0.f;
  #pragma unroll
  for (int p = 0; p < 8; ++p) {
    const float* wr = ow + (size_t)(2 * p) * E_DIM + lane * 8;   // row 2p = offsets[...,0]
    const float4 w0 = *(const float4*)wr;
    const float4 w1 = *(const float4*)(wr + 4);
    float acc = q0.x*w0.x + q0.y*w0.y + q0.z*w0.z + q0.w*w0.w
              + q1.x*w1.x + q1.y*w1.y + q1.z*w1.z + q1.w*w1.w;
    #pragma unroll
    for (int d = 32; d; d >>= 1) acc += __shfl_xor(acc, d, 64);
    if ((lane & 7) == p) myoff = acc;
  }
  if (lane < 8) {
    float off = myoff + ob[2 * lane];
    float val = (float)s + off;
    int id = (int)truncf(val);
    id = id < 0 ? 0 : (id > S_LEN - 1 ? S_LEN - 1 : id);
    idx[n * 8 + lane] = id;
  }
}

// ---------------- bf16 MFMA GEMM, m201-style: BM=BN=256, BK=64, 8 waves (2x4), ----------------
// wave tile 128x64, 128 KB LDS dbuf, phase-split K-tiles with counted staging,
// raw s_barrier + manual waitcnt + sched_barrier hygiene, setprio on MFMA clusters.
// OUT_MODE: 1 = bf16 split store (qkv, z selects A/W/bias/out), 0 = fp32 d_out.
template<int OUT_MODE>
__global__ __launch_bounds__(512, 2)
void gemm8_kernel(const unsigned short* __restrict__ A0, const unsigned short* __restrict__ A1,
                  const unsigned short* __restrict__ A2, const unsigned short* __restrict__ W,
                  const float* __restrict__ bias, void* __restrict__ Cout)
{
  __shared__ __align__(16) unsigned short sA[2][256 * 64];   // 64 KB
  __shared__ __align__(16) unsigned short sB[2][256 * 64];   // 64 KB

  const int z = blockIdx.z;
  const unsigned short* A  = (z == 0) ? A0 : ((z == 1) ? A1 : A2);
  const unsigned short* Wz = W + (size_t)z * E_DIM * E_DIM;

  const int t    = threadIdx.x;
  const int lane = t & 63;
  const int wid  = t >> 6;        // 0..7
  const int wm   = wid >> 2;      // 0..1 : wave rows [wm*128, +128)
  const int wn   = wid & 3;       // 0..3 : wave cols [wn*64, +64)
  const size_t m0 = (size_t)blockIdx.x * 256;
  const size_t n0 = (size_t)blockIdx.y * 256;

  // staging: wave wid stages 16 rows per half (2 x gload16 of 8 rows each).
  // lane -> row += lane>>3, chunk = (lane&7) ^ (lane>>3)  (pre-swizzled source, rule #21)
  const unsigned short* gA = A  + (m0 + wid * 16 + (lane >> 3)) * E_DIM + (((lane & 7) ^ (lane >> 3)) << 3);
  const unsigned short* gB = Wz + (n0 + wid * 16 + (lane >> 3)) * E_DIM + (((lane & 7) ^ (lane >> 3)) << 3);

#define STG_A(slot, kt, h) do { \
    gload16(gA + (size_t)((h) * 128) * E_DIM + (kt) * 64,     &sA[slot][((h) * 128 + wid * 16) * 64]); \
    gload16(gA + (size_t)((h) * 128 + 8) * E_DIM + (kt) * 64, &sA[slot][((h) * 128 + wid * 16 + 8) * 64]); \
  } while (0)
#define STG_B(slot, kt, h) do { \
    gload16(gB + (size_t)((h) * 128) * E_DIM + (kt) * 64,     &sB[slot][((h) * 128 + wid * 16) * 64]); \
    gload16(gB + (size_t)((h) * 128 + 8) * E_DIM + (kt) * 64, &sB[slot][((h) * 128 + wid * 16 + 8) * 64]); \
  } while (0)

  f32x4_t acc[8][4];
  #pragma unroll
  for (int i = 0; i < 8; ++i)
    #pragma unroll
    for (int j = 0; j < 4; ++j)
      acc[i][j] = (f32x4_t){0.f, 0.f, 0.f, 0.f};

  bf16x8_t af[4][2], bf0[2][2], bf1[2][2];
  const int fr = lane & 15;
  const int rx = fr & 7;          // row&7 for read-side swizzle
  const int kc = lane >> 4;       // k-chunk base 0..3

#define RD_A(sl, msub) do { _Pragma("unroll") for (int i_ = 0; i_ < 4; ++i_) { \
    const int row = wm * 128 + ((msub) * 4 + i_) * 16 + fr; \
    af[i_][0] = *(const bf16x8_t*)&sA[sl][row * 64 + ((kc ^ rx) << 3)]; \
    af[i_][1] = *(const bf16x8_t*)&sA[sl][row * 64 + (((4 + kc) ^ rx) << 3)]; \
  } } while (0)
#define RD_B(sl, dst, nsub) do { _Pragma("unroll") for (int j_ = 0; j_ < 2; ++j_) { \
    const int row = wn * 64 + ((nsub) * 2 + j_) * 16 + fr; \
    dst[j_][0] = *(const bf16x8_t*)&sB[sl][row * 64 + ((kc ^ rx) << 3)]; \
    dst[j_][1] = *(const bf16x8_t*)&sB[sl][row * 64 + (((4 + kc) ^ rx) << 3)]; \
  } } while (0)
#define MFMA_Q(ms, ns, bb) do { _Pragma("unroll") for (int i_ = 0; i_ < 4; ++i_) \
    _Pragma("unroll") for (int j_ = 0; j_ < 2; ++j_) { \
      acc[(ms)*4+i_][(ns)*2+j_] = __builtin_amdgcn_mfma_f32_16x16x32_bf16(af[i_][0], bb[j_][0], acc[(ms)*4+i_][(ns)*2+j_], 0, 0, 0); \
      acc[(ms)*4+i_][(ns)*2+j_] = __builtin_amdgcn_mfma_f32_16x16x32_bf16(af[i_][1], bb[j_][1], acc[(ms)*4+i_][(ns)*2+j_], 0, 0, 0); \
  } } while (0)

  // prologue: stage tile 0 fully, drain, barrier
  STG_A(0, 0, 0); STG_B(0, 0, 0); STG_A(0, 0, 1); STG_B(0, 0, 1);
  asm volatile("s_waitcnt vmcnt(0)" ::: "memory");
  __builtin_amdgcn_sched_barrier(0);
  __builtin_amdgcn_s_barrier();

  for (int kt = 0; kt < 8; ++kt) {            // 512 / 64 K-tiles, dbuf by kt&1
    const int sl = kt & 1;
    // ---- phase A: frags A0,B0 ; stage half 0 of t+1 ----
    RD_A(sl, 0); RD_B(sl, bf0, 0);
    if (kt < 7) { STG_A(sl ^ 1, kt + 1, 0); STG_B(sl ^ 1, kt + 1, 0); }
    __builtin_amdgcn_s_barrier();
    asm volatile("s_waitcnt lgkmcnt(0)" ::: "memory");
    __builtin_amdgcn_sched_barrier(0);
    __builtin_amdgcn_s_setprio(1);
    MFMA_Q(0, 0, bf0);
    __builtin_amdgcn_s_setprio(0);
    __builtin_amdgcn_sched_barrier(0);
    __builtin_amdgcn_s_barrier();
    // ---- phase B: frags B1 ; stage half 1 of t+1 ----
    RD_B(sl, bf1, 1);
    if (kt < 7) { STG_A(sl ^ 1, kt + 1, 1); STG_B(sl ^ 1, kt + 1, 1); }
    __builtin_amdgcn_s_barrier();
    asm volatile("s_waitcnt lgkmcnt(0)" ::: "memory");
    __builtin_amdgcn_sched_barrier(0);
    __builtin_amdgcn_s_setprio(1);
    MFMA_Q(0, 1, bf1);
    __builtin_amdgcn_s_setprio(0);
    __builtin_amdgcn_sched_barrier(0);
    __builtin_amdgcn_s_barrier();
    // ---- phase C: frags A1 ; 32 MFMA ; tile-boundary drain ----
    RD_A(sl, 1);
    __builtin_amdgcn_s_barrier();
    asm volatile("s_waitcnt lgkmcnt(0)" ::: "memory");
    __builtin_amdgcn_sched_barrier(0);
    __builtin_amdgcn_s_setprio(1);
    MFMA_Q(1, 0, bf0);
    MFMA_Q(1, 1, bf1);
    __builtin_amdgcn_s_setprio(0);
    __builtin_amdgcn_sched_barrier(0);
    if (kt < 7) {
      asm volatile("s_waitcnt vmcnt(0)" ::: "memory");   // t+1 staged (issued 1-2 phases ago)
      __builtin_amdgcn_sched_barrier(0);
      __builtin_amdgcn_s_barrier();
    }
  }
#undef STG_A
#undef STG_B
#undef RD_A
#undef RD_B
#undef MFMA_Q

  // Epilogue: D row = (lane>>4)*4 + r, col = lane&15  (m89-verified C/D layout)
  unsigned short* Cb = (unsigned short*)Cout + (size_t)z * NTOK * E_DIM;
  float* Cf = (float*)Cout;
  #pragma unroll
  for (int mi = 0; mi < 8; ++mi) {
    const int row = (int)m0 + wm * 128 + mi * 16 + (lane >> 4) * 4;
    #pragma unroll
    for (int nj = 0; nj < 4; ++nj) {
      const int col = (int)n0 + wn * 64 + nj * 16 + fr;
      const float bv = bias[z * E_DIM + col];
      #pragma unroll
      for (int r = 0; r < 4; ++r) {
        const float val = acc[mi][nj][r] + bv;
        if constexpr (OUT_MODE)
          Cb[(size_t)(row + r) * E_DIM + col] = __builtin_bit_cast(unsigned short, (__bf16)val);
        else
          Cf[(size_t)(row + r) * E_DIM + col] = val;
      }
    }
  }
}

// ---------------- attention: gather projected rows, softmax over P=8, ctx (bf16) ----------------
__global__ __launch_bounds__(256)
void attn_kernel(const unsigned short* __restrict__ Qp, const unsigned short* __restrict__ Kp,
                 const unsigned short* __restrict__ Vp, const int* __restrict__ idx,
                 unsigned short* __restrict__ ctx)
{
  const int wid  = threadIdx.x >> 6;
  const int lane = threadIdx.x & 63;
  const int n = blockIdx.x * 4 + wid;
  const int b = n >> 11;
  const int h = lane >> 3;
  const int p = lane & 7;

  const int id = idx[n * 8 + p];
  const size_t krow = ((size_t)(b << 11) + id) * E_DIM + h * 64;
  const unsigned short* qb = Qp + (size_t)n * E_DIM + h * 64;

  float sc = 0.f;
  #pragma unroll
  for (int j = 0; j < 8; ++j) {
    u16x8_t qv = *(const u16x8_t*)(qb + j * 8);
    u16x8_t kv = *(const u16x8_t*)(Kp + krow + j * 8);
    #pragma unroll
    for (int e = 0; e < 8; ++e) sc += bf2f(qv[e]) * bf2f(kv[e]);
  }
  sc *= 0.125f;  // 1/sqrt(64)

  float m = sc;
  m = fmaxf(m, __shfl_xor(m, 1, 64));
  m = fmaxf(m, __shfl_xor(m, 2, 64));
  m = fmaxf(m, __shfl_xor(m, 4, 64));
  const float ex = __expf(sc - m);
  float dsum = ex;
  dsum += __shfl_xor(dsum, 1, 64);
  dsum += __shfl_xor(dsum, 2, 64);
  dsum += __shfl_xor(dsum, 4, 64);
  const float attn = ex / dsum;

  const int d0 = p * 8;
  float cacc[8];
  #pragma unroll
  for (int j = 0; j < 8; ++j) cacc[j] = 0.f;
  #pragma unroll
  for (int pp = 0; pp < 8; ++pp) {
    const float ap = __shfl(attn, (lane & 56) + pp, 64);
    const int  idp = __shfl(id,   (lane & 56) + pp, 64);
    const unsigned short* vb = Vp + ((size_t)(b << 11) + idp) * E_DIM + h * 64 + d0;
    u16x8_t vv = *(const u16x8_t*)vb;
    #pragma unroll
    for (int j = 0; j < 8; ++j) cacc[j] += ap * bf2f(vv[j]);
  }
  u16x8_t cc;
  #pragma unroll
  for (int j = 0; j < 8; ++j) cc[j] = __builtin_bit_cast(unsigned short, (__bf16)cacc[j]);
  *(u16x8_t*)(ctx + (size_t)n * E_DIM + h * 64 + d0) = cc;
}

extern "C" void kernel_launch(void* const* d_in, const int* in_sizes, int n_in,
                              void* d_out, int out_size, void* d_ws, size_t ws_size,
                              hipStream_t stream) {
  const float* q        = (const float*)d_in[0];
  const float* k        = (const float*)d_in[1];
  const float* v        = (const float*)d_in[2];
  const float* offset_w = (const float*)d_in[3];
  const float* offset_b = (const float*)d_in[4];
  const float* in_proj_w = (const float*)d_in[5];
  const float* in_proj_b = (const float*)d_in[6];
  const float* out_w    = (const float*)d_in[7];
  const float* out_b    = (const float*)d_in[8];

  char* ws = (char*)d_ws;
  // ws layout (u16 elements):
  // Qbf | Kbf | Vbf | Wb(786432) | OWb(262144) | Qp | Kp | Vp | idx(int)
  unsigned short* Qbf = (unsigned short*)ws;
  unsigned short* Kbf = Qbf + (size_t)NTOK * E_DIM;
  unsigned short* Vbf = Kbf + (size_t)NTOK * E_DIM;
  unsigned short* Wb  = Vbf + (size_t)NTOK * E_DIM;
  unsigned short* OWb = Wb + (size_t)3 * E_DIM * E_DIM;
  unsigned short* Qp  = OWb + (size_t)E_DIM * E_DIM;
  unsigned short* Kp  = Qp + (size_t)NTOK * E_DIM;
  unsigned short* Vp  = Kp + (size_t)NTOK * E_DIM;
  int* idxb = (int*)(Vp + (size_t)NTOK * E_DIM);
  unsigned short* ctxb = Qbf;   // alias: Qbf dead after qkv GEMM

  prepass_kernel<<<12800, 256, 0, stream>>>(q, k, v, in_proj_w, out_w, offset_w, offset_b,
                                            idxb, Qbf, Kbf, Vbf, Wb, OWb);
  gemm8_kernel<1><<<dim3(NTOK / 256, E_DIM / 256, 3), 512, 0, stream>>>(
      Qbf, Kbf, Vbf, Wb, in_proj_b, (void*)Qp);
  attn_kernel<<<NTOK / 4, 256, 0, stream>>>(Qp, Kp, Vp, idxb, ctxb);
  gemm8_kernel<0><<<dim3(NTOK / 256, E_DIM / 256, 1), 512, 0, stream>>>(
      ctxb, ctxb, ctxb, OWb, out_b, d_out);
}

// Round 8
// 100.529 us; speedup vs baseline: 1.1190x; 1.1190x over previous
//
#include <hip/hip_runtime.h>

#define S_LEN 2048
#define E_DIM 512
#define NTOK  16384   // B*S = 8*2048
#define QBLK  1024    // prepass q-part blocks: 4 waves x 4 tokens = 16 tokens/block

typedef __bf16 bf16x8_t __attribute__((ext_vector_type(8)));
typedef float f32x4_t __attribute__((ext_vector_type(4)));
typedef unsigned short u16x8_t __attribute__((ext_vector_type(8)));

__device__ __forceinline__ float bf2f(unsigned short h) {
  return __uint_as_float(((unsigned)h) << 16);
}
// native casts -> compiler emits v_cvt_pk_bf16_f32 (m240: don't hand-roll)
__device__ __forceinline__ u16x8_t cvt8n(float4 a, float4 b) {
  bf16x8_t t;
  t[0] = (__bf16)a.x; t[1] = (__bf16)a.y; t[2] = (__bf16)a.z; t[3] = (__bf16)a.w;
  t[4] = (__bf16)b.x; t[5] = (__bf16)b.y; t[6] = (__bf16)b.z; t[7] = (__bf16)b.w;
  union { bf16x8_t h; u16x8_t u; } cv; cv.h = t; return cv.u;
}
// async global->LDS, 16B per lane; LDS dest = wave-uniform base + lane*16
__device__ __forceinline__ void gload16(const void* g, void* l) {
  __builtin_amdgcn_global_load_lds(
      (const __attribute__((address_space(1))) unsigned int*)g,
      (__attribute__((address_space(3))) unsigned int*)l, 16, 0, 0);
}

// ---------------- prepass ----------------
// blocks [0, QBLK): offsets (lane-parallel) + q->bf16.  blocks [QBLK, QBLK+8704): cvt k,v,W,OW.
__global__ __launch_bounds__(256)
void prepass_kernel(const float* __restrict__ q, const float* __restrict__ k,
                    const float* __restrict__ v, const float* __restrict__ ipw,
                    const float* __restrict__ outw, const float* __restrict__ ow,
                    const float* __restrict__ ob, int* __restrict__ idx,
                    unsigned short* __restrict__ Qbf, unsigned short* __restrict__ Kb,
                    unsigned short* __restrict__ Vb, unsigned short* __restrict__ Wb,
                    unsigned short* __restrict__ OWb)
{
  const int bid = blockIdx.x;
  if (bid >= QBLK) {
    const int cb = bid - QBLK;
    const float* src; unsigned short* dst; size_t off;
    if (cb < 4096)      { src = k;    dst = Kb;  off = (size_t)cb * 2048; }
    else if (cb < 8192) { src = v;    dst = Vb;  off = (size_t)(cb - 4096) * 2048; }
    else if (cb < 8576) { src = ipw;  dst = Wb;  off = (size_t)(cb - 8192) * 2048; }
    else                { src = outw; dst = OWb; off = (size_t)(cb - 8576) * 2048; }
    const size_t i = off + (size_t)threadIdx.x * 8;
    const float4 a = *(const float4*)(src + i);
    const float4 b = *(const float4*)(src + i + 4);
    *(u16x8_t*)(dst + i) = cvt8n(a, b);
    return;
  }

  // ---- offsets + q->bf16, 16 tokens per block ----
  // padded layout: element e -> (e>>6)*68 + (e&63); per-instr banks disjoint per j.
  __shared__ float wl[8][544];   // even offset_w rows 0,2,..,14
  __shared__ float ql[4][544];   // one token row per wave

  {
    const int r  = threadIdx.x >> 5;            // 0..7
    const int e0 = (threadIdx.x & 31) * 16;
    const float* src = ow + (size_t)(2 * r) * E_DIM + e0;
    #pragma unroll
    for (int c = 0; c < 4; ++c) {
      const int e = e0 + c * 4;
      *(float4*)&wl[r][(e >> 6) * 68 + (e & 63)] = *(const float4*)(src + c * 4);
    }
  }
  __syncthreads();

  const int w    = threadIdx.x >> 6;
  const int lane = threadIdx.x & 63;
  const int j    = lane >> 3;     // segment 0..7 (64 elems each)
  const int p    = lane & 7;      // sample 0..7

  for (int it = 0; it < 4; ++it) {
    const int n = bid * 16 + w * 4 + it;
    // stage q row (coalesced) + bf16 conversion write
    const float* qr = q + (size_t)n * E_DIM + lane * 8;
    const float4 q0 = *(const float4*)qr;
    const float4 q1 = *(const float4*)(qr + 4);
    *(u16x8_t*)(Qbf + (size_t)n * E_DIM + lane * 8) = cvt8n(q0, q1);
    const int e  = lane * 8;
    const int ph = (e >> 6) * 68 + (e & 63);
    *(float4*)&ql[w][ph]     = q0;
    *(float4*)&ql[w][ph + 4] = q1;   // same 64-block, no pad crossing

    // lane (p, j): partial dot of q[seg j] . offset_w[2p][seg j]
    float acc = 0.f;
    #pragma unroll
    for (int i4 = 0; i4 < 16; ++i4) {
      const float4 qv = *(const float4*)&ql[w][j * 68 + i4 * 4];
      const float4 wv = *(const float4*)&wl[p][j * 68 + i4 * 4];
      acc = fmaf(qv.x, wv.x, acc); acc = fmaf(qv.y, wv.y, acc);
      acc = fmaf(qv.z, wv.z, acc); acc = fmaf(qv.w, wv.w, acc);
    }
    acc += __shfl_xor(acc, 8, 64);
    acc += __shfl_xor(acc, 16, 64);
    acc += __shfl_xor(acc, 32, 64);
    if (lane < 8) {
      const float val = (float)(n & (S_LEN - 1)) + acc + ob[2 * lane];
      int id = (int)truncf(val);               // trunc toward zero, then clip (matches ref)
      id = id < 0 ? 0 : (id > S_LEN - 1 ? S_LEN - 1 : id);
      idx[n * 8 + lane] = id;
    }
    __syncthreads();   // ql[w] reuse guard (cheap, keeps waves roughly together)
  }
}

// ---------------- bf16 MFMA GEMM: C(16384 x 512) = A @ W^T + bias (all-bf16) ----------------
// Round-5 proven structure: 128x128 tile, BK=64, 4 waves (2x2) of 64x64 wave tiles,
// global_load_lds with pre-swizzled source (chunk ^= row&7 involution, rule #21),
// 64 KB LDS dbuf -> 2 blocks/CU (m114 implicit cross-block overlap).
// Grid (m, n, z): same-m blocks 128 apart -> same XCD -> A L2-reuse.
template<int OUT_BF16>
__global__ __launch_bounds__(256, 2)
void gemm_kernel(const unsigned short* __restrict__ A0, const unsigned short* __restrict__ A1,
                 const unsigned short* __restrict__ A2, const unsigned short* __restrict__ W,
                 const float* __restrict__ bias, void* __restrict__ Cout)
{
  __shared__ __align__(16) unsigned short sA[2][128 * 64];
  __shared__ __align__(16) unsigned short sB[2][128 * 64];

  const int z = blockIdx.z;
  const unsigned short* A = (z == 0) ? A0 : ((z == 1) ? A1 : A2);
  const unsigned short* Wz = W + (size_t)z * E_DIM * E_DIM;
  const float* bz = bias + (size_t)z * E_DIM;

  const int t    = threadIdx.x;
  const int lane = t & 63;
  const int wid  = t >> 6;        // 0..3
  const int wm   = wid >> 1;      // 0..1
  const int wn   = wid & 1;       // 0..1
  const size_t m0 = (size_t)blockIdx.x * 128;
  const size_t n0 = (size_t)blockIdx.y * 128;

  const int srow0  = wid * 32;
  const int schunk = (lane & 7) ^ (lane >> 3);
  const unsigned short* gA = A  + (m0 + srow0 + (lane >> 3)) * E_DIM + schunk * 8;
  const unsigned short* gB = Wz + (n0 + srow0 + (lane >> 3)) * E_DIM + schunk * 8;

#define STAGE(buf, k0) do { \
    _Pragma("unroll") \
    for (int i_ = 0; i_ < 4; ++i_) { \
      gload16(gA + (size_t)(i_ * 8) * E_DIM + (k0), &sA[buf][(srow0 + i_ * 8) * 64]); \
      gload16(gB + (size_t)(i_ * 8) * E_DIM + (k0), &sB[buf][(srow0 + i_ * 8) * 64]); \
    } } while (0)

  f32x4_t acc[4][4];
  #pragma unroll
  for (int i = 0; i < 4; ++i)
    #pragma unroll
    for (int j = 0; j < 4; ++j)
      acc[i][j] = (f32x4_t){0.f, 0.f, 0.f, 0.f};

  STAGE(0, 0);
  int cur = 0;
  const int fr = lane & 15;
  const int ck0 = lane >> 4;      // fragment k-chunk base (0..3)

  for (int kt = 0; kt < 8; ++kt) {            // 512 / 64
    __syncthreads();                          // staged tile (cur) complete & visible
    if (kt < 7) STAGE(cur ^ 1, (kt + 1) * 64);
    #pragma unroll
    for (int kk = 0; kk < 64; kk += 32) {
      const int ckb = (kk >> 3) + ck0;        // 0..7
      bf16x8_t af[4], bfv[4];
      #pragma unroll
      for (int i = 0; i < 4; ++i) {
        const int ra = wm * 64 + i * 16 + fr;
        af[i] = *(const bf16x8_t*)&sA[cur][ra * 64 + ((ckb ^ (ra & 7)) << 3)];
      }
      #pragma unroll
      for (int j = 0; j < 4; ++j) {
        const int rb = wn * 64 + j * 16 + fr;
        bfv[j] = *(const bf16x8_t*)&sB[cur][rb * 64 + ((ckb ^ (rb & 7)) << 3)];
      }
      #pragma unroll
      for (int i = 0; i < 4; ++i)
        #pragma unroll
        for (int j = 0; j < 4; ++j)
          acc[i][j] = __builtin_amdgcn_mfma_f32_16x16x32_bf16(af[i], bfv[j], acc[i][j], 0, 0, 0);
    }
    cur ^= 1;
  }
#undef STAGE

  // Epilogue: D row = (lane>>4)*4 + r, col = lane&15  (m89-verified C/D layout)
  unsigned short* Cb = (unsigned short*)Cout + (size_t)z * NTOK * E_DIM;
  float* Cf = (float*)Cout;
  #pragma unroll
  for (int i = 0; i < 4; ++i) {
    const int row = (int)m0 + wm * 64 + i * 16 + (lane >> 4) * 4;
    #pragma unroll
    for (int j = 0; j < 4; ++j) {
      const int col = (int)n0 + wn * 64 + j * 16 + fr;
      const float bv = bz[col];
      #pragma unroll
      for (int r = 0; r < 4; ++r) {
        const float val = acc[i][j][r] + bv;
        if constexpr (OUT_BF16)
          Cb[(size_t)(row + r) * E_DIM + col] = __builtin_bit_cast(unsigned short, (__bf16)val);
        else
          Cf[(size_t)(row + r) * E_DIM + col] = val;
      }
    }
  }
}

// ---------------- attention: gather projected rows, softmax over P=8, ctx (bf16) ----------------
__global__ __launch_bounds__(256)
void attn_kernel(const unsigned short* __restrict__ Qp, const unsigned short* __restrict__ Kp,
                 const unsigned short* __restrict__ Vp, const int* __restrict__ idx,
                 unsigned short* __restrict__ ctx)
{
  const int wid  = threadIdx.x >> 6;
  const int lane = threadIdx.x & 63;
  const int n = blockIdx.x * 4 + wid;
  const int b = n >> 11;
  const int h = lane >> 3;
  const int p = lane & 7;

  const int id = idx[n * 8 + p];
  const size_t krow = ((size_t)(b << 11) + id) * E_DIM + h * 64;
  const unsigned short* qb = Qp + (size_t)n * E_DIM + h * 64;

  float sc = 0.f;
  #pragma unroll
  for (int j = 0; j < 8; ++j) {
    u16x8_t qv = *(const u16x8_t*)(qb + j * 8);
    u16x8_t kv = *(const u16x8_t*)(Kp + krow + j * 8);
    #pragma unroll
    for (int e = 0; e < 8; ++e) sc += bf2f(qv[e]) * bf2f(kv[e]);
  }
  sc *= 0.125f;  // 1/sqrt(64)

  float m = sc;
  m = fmaxf(m, __shfl_xor(m, 1, 64));
  m = fmaxf(m, __shfl_xor(m, 2, 64));
  m = fmaxf(m, __shfl_xor(m, 4, 64));
  const float ex = __expf(sc - m);
  float dsum = ex;
  dsum += __shfl_xor(dsum, 1, 64);
  dsum += __shfl_xor(dsum, 2, 64);
  dsum += __shfl_xor(dsum, 4, 64);
  const float attn = ex / dsum;

  const int d0 = p * 8;
  float cacc[8];
  #pragma unroll
  for (int j = 0; j < 8; ++j) cacc[j] = 0.f;
  #pragma unroll
  for (int pp = 0; pp < 8; ++pp) {
    const float ap = __shfl(attn, (lane & 56) + pp, 64);
    const int  idp = __shfl(id,   (lane & 56) + pp, 64);
    const unsigned short* vb = Vp + ((size_t)(b << 11) + idp) * E_DIM + h * 64 + d0;
    u16x8_t vv = *(const u16x8_t*)vb;
    #pragma unroll
    for (int j = 0; j < 8; ++j) cacc[j] += ap * bf2f(vv[j]);
  }
  u16x8_t cc;
  #pragma unroll
  for (int j = 0; j < 8; ++j) cc[j] = __builtin_bit_cast(unsigned short, (__bf16)cacc[j]);
  *(u16x8_t*)(ctx + (size_t)n * E_DIM + h * 64 + d0) = cc;
}

extern "C" void kernel_launch(void* const* d_in, const int* in_sizes, int n_in,
                              void* d_out, int out_size, void* d_ws, size_t ws_size,
                              hipStream_t stream) {
  const float* q        = (const float*)d_in[0];
  const float* k        = (const float*)d_in[1];
  const float* v        = (const float*)d_in[2];
  const float* offset_w = (const float*)d_in[3];
  const float* offset_b = (const float*)d_in[4];
  const float* in_proj_w = (const float*)d_in[5];
  const float* in_proj_b = (const float*)d_in[6];
  const float* out_w    = (const float*)d_in[7];
  const float* out_b    = (const float*)d_in[8];

  char* ws = (char*)d_ws;
  // ws layout (u16 elements):
  // Qbf | Kbf | Vbf | Wb(786432) | OWb(262144) | Qp | Kp | Vp | idx(int)
  unsigned short* Qbf = (unsigned short*)ws;
  unsigned short* Kbf = Qbf + (size_t)NTOK * E_DIM;
  unsigned short* Vbf = Kbf + (size_t)NTOK * E_DIM;
  unsigned short* Wb  = Vbf + (size_t)NTOK * E_DIM;
  unsigned short* OWb = Wb + (size_t)3 * E_DIM * E_DIM;
  unsigned short* Qp  = OWb + (size_t)E_DIM * E_DIM;
  unsigned short* Kp  = Qp + (size_t)NTOK * E_DIM;
  unsigned short* Vp  = Kp + (size_t)NTOK * E_DIM;
  int* idxb = (int*)(Vp + (size_t)NTOK * E_DIM);
  unsigned short* ctxb = Qbf;   // alias: Qbf dead after qkv GEMM

  prepass_kernel<<<QBLK + 8704, 256, 0, stream>>>(q, k, v, in_proj_w, out_w, offset_w,
                                                  offset_b, idxb, Qbf, Kbf, Vbf, Wb, OWb);
  gemm_kernel<1><<<dim3(NTOK / 128, E_DIM / 128, 3), 256, 0, stream>>>(
      Qbf, Kbf, Vbf, Wb, in_proj_b, (void*)Qp);
  attn_kernel<<<NTOK / 4, 256, 0, stream>>>(Qp, Kp, Vp, idxb, ctxb);
  gemm_kernel<0><<<dim3(NTOK / 128, E_DIM / 128, 1), 256, 0, stream>>>(
      ctxb, ctxb, ctxb, OWb, out_b, d_out);
}

// Round 10
// 100.054 us; speedup vs baseline: 1.1243x; 1.0047x over previous
//
#include <hip/hip_runtime.h>

#define S_LEN 2048
#define E_DIM 512
#define NTOK  16384   // B*S = 8*2048
#define QBLK  1024    // prepass q-part blocks: 4 waves x 4 tokens = 16 tokens/block
#define CVTBLK 4096   // prepass cvt blocks (grid-stride)

typedef __bf16 bf16x8_t __attribute__((ext_vector_type(8)));
typedef __bf16 bf16x4_t __attribute__((ext_vector_type(4)));
typedef float f32x4_t __attribute__((ext_vector_type(4)));
typedef unsigned short u16x8_t __attribute__((ext_vector_type(8)));
typedef unsigned short u16x4_t __attribute__((ext_vector_type(4)));

__device__ __forceinline__ float bf2f(unsigned short h) {
  return __uint_as_float(((unsigned)h) << 16);
}
// native casts -> compiler emits v_cvt_pk_bf16_f32 (m240: don't hand-roll)
__device__ __forceinline__ u16x8_t cvt8n(float4 a, float4 b) {
  bf16x8_t t;
  t[0] = (__bf16)a.x; t[1] = (__bf16)a.y; t[2] = (__bf16)a.z; t[3] = (__bf16)a.w;
  t[4] = (__bf16)b.x; t[5] = (__bf16)b.y; t[6] = (__bf16)b.z; t[7] = (__bf16)b.w;
  union { bf16x8_t h; u16x8_t u; } cv; cv.h = t; return cv.u;
}
__device__ __forceinline__ u16x4_t cvt4n(float4 a) {
  bf16x4_t t;
  t[0] = (__bf16)a.x; t[1] = (__bf16)a.y; t[2] = (__bf16)a.z; t[3] = (__bf16)a.w;
  union { bf16x4_t h; u16x4_t u; } cv; cv.h = t; return cv.u;
}
// async global->LDS, 16B per lane; LDS dest = wave-uniform base + lane*16
__device__ __forceinline__ void gload16(const void* g, void* l) {
  __builtin_amdgcn_global_load_lds(
      (const __attribute__((address_space(1))) unsigned int*)g,
      (__attribute__((address_space(3))) unsigned int*)l, 16, 0, 0);
}

// ---------------- prepass ----------------
// blocks [0, QBLK): offsets (lane-parallel) + q->bf16.
// blocks [QBLK, QBLK+CVTBLK): grid-stride fp32->bf16 cvt of k|v|ipw|outw (16B granules).
__global__ __launch_bounds__(256)
void prepass_kernel(const float* __restrict__ q, const float* __restrict__ k,
                    const float* __restrict__ v, const float* __restrict__ ipw,
                    const float* __restrict__ outw, const float* __restrict__ ow,
                    const float* __restrict__ ob, int* __restrict__ idx,
                    unsigned short* __restrict__ Qbf, unsigned short* __restrict__ Kb,
                    unsigned short* __restrict__ Vb, unsigned short* __restrict__ Wb,
                    unsigned short* __restrict__ OWb)
{
  const int bid = blockIdx.x;
  if (bid >= QBLK) {
    // granule = 4 fp32 = 16B read / 8B write. Segment bounds in granules:
    // k: 8388608 elems = 2097152 g | v: +2097152 | ipw: 786432 e = 196608 g | outw: 262144 e = 65536 g
    const size_t NG = 4456448;
    const size_t gstride = (size_t)CVTBLK * 256;
    for (size_t g = (size_t)(bid - QBLK) * 256 + threadIdx.x; g < NG; g += gstride) {
      const float* src; unsigned short* dst; size_t e;
      if (g < 2097152)      { src = k;    dst = Kb;  e = g * 4; }
      else if (g < 4194304) { src = v;    dst = Vb;  e = (g - 2097152) * 4; }
      else if (g < 4390912) { src = ipw;  dst = Wb;  e = (g - 4194304) * 4; }
      else                  { src = outw; dst = OWb; e = (g - 4390912) * 4; }
      *(u16x4_t*)(dst + e) = cvt4n(*(const float4*)(src + e));
    }
    return;
  }

  // ---- offsets + q->bf16, 16 tokens per block ----
  // wl row stride 548 (548 % 32 == 4): p -> 8 distinct banks, kills the 8-way conflict.
  __shared__ float wl[8][548];   // even offset_w rows 0,2,..,14 (elem e -> (e>>6)*68 + (e&63))
  __shared__ float ql[4][548];   // one token row per wave

  {
    const int r  = threadIdx.x >> 5;            // 0..7
    const int e0 = (threadIdx.x & 31) * 16;
    const float* src = ow + (size_t)(2 * r) * E_DIM + e0;
    #pragma unroll
    for (int c = 0; c < 4; ++c) {
      const int e = e0 + c * 4;
      *(float4*)&wl[r][(e >> 6) * 68 + (e & 63)] = *(const float4*)(src + c * 4);
    }
  }
  __syncthreads();

  const int w    = threadIdx.x >> 6;
  const int lane = threadIdx.x & 63;
  const int j    = lane >> 3;     // segment 0..7 (64 elems each)
  const int p    = lane & 7;      // sample 0..7

  for (int it = 0; it < 4; ++it) {
    const int n = bid * 16 + w * 4 + it;
    // stage q row (coalesced) + bf16 conversion write
    const float* qr = q + (size_t)n * E_DIM + lane * 8;
    const float4 q0 = *(const float4*)qr;
    const float4 q1 = *(const float4*)(qr + 4);
    *(u16x8_t*)(Qbf + (size_t)n * E_DIM + lane * 8) = cvt8n(q0, q1);
    const int e  = lane * 8;
    const int ph = (e >> 6) * 68 + (e & 63);
    *(float4*)&ql[w][ph]     = q0;
    *(float4*)&ql[w][ph + 4] = q1;   // same 64-block, no pad crossing

    // lane (p, j): partial dot of q[seg j] . offset_w[2p][seg j]
    float acc = 0.f;
    #pragma unroll
    for (int i4 = 0; i4 < 16; ++i4) {
      const float4 qv = *(const float4*)&ql[w][j * 68 + i4 * 4];
      const float4 wv = *(const float4*)&wl[p][j * 68 + i4 * 4];
      acc = fmaf(qv.x, wv.x, acc); acc = fmaf(qv.y, wv.y, acc);
      acc = fmaf(qv.z, wv.z, acc); acc = fmaf(qv.w, wv.w, acc);
    }
    acc += __shfl_xor(acc, 8, 64);
    acc += __shfl_xor(acc, 16, 64);
    acc += __shfl_xor(acc, 32, 64);
    if (lane < 8) {
      const float val = (float)(n & (S_LEN - 1)) + acc + ob[2 * lane];
      int id = (int)truncf(val);               // trunc toward zero, then clip (matches ref)
      id = id < 0 ? 0 : (id > S_LEN - 1 ? S_LEN - 1 : id);
      idx[n * 8 + lane] = id;
    }
    __syncthreads();   // ql[w] reuse guard
  }
}

// ---------------- bf16 MFMA GEMM: C(16384 x 512) = A @ W^T + bias (all-bf16) ----------------
// Round-5 proven structure: 128x128 tile, BK=64, 4 waves (2x2) of 64x64 wave tiles,
// global_load_lds with pre-swizzled source (chunk ^= row&7 involution, rule #21),
// 64 KB LDS dbuf -> 2 blocks/CU (m114 implicit cross-block overlap).
// Grid (m, n, z): same-m blocks 128 apart -> same XCD -> A L2-reuse.
template<int OUT_BF16>
__global__ __launch_bounds__(256, 2)
void gemm_kernel(const unsigned short* __restrict__ A0, const unsigned short* __restrict__ A1,
                 const unsigned short* __restrict__ A2, const unsigned short* __restrict__ W,
                 const float* __restrict__ bias, void* __restrict__ Cout)
{
  __shared__ __align__(16) unsigned short sA[2][128 * 64];
  __shared__ __align__(16) unsigned short sB[2][128 * 64];

  const int z = blockIdx.z;
  const unsigned short* A = (z == 0) ? A0 : ((z == 1) ? A1 : A2);
  const unsigned short* Wz = W + (size_t)z * E_DIM * E_DIM;
  const float* bz = bias + (size_t)z * E_DIM;

  const int t    = threadIdx.x;
  const int lane = t & 63;
  const int wid  = t >> 6;        // 0..3
  const int wm   = wid >> 1;      // 0..1
  const int wn   = wid & 1;       // 0..1
  const size_t m0 = (size_t)blockIdx.x * 128;
  const size_t n0 = (size_t)blockIdx.y * 128;

  const int srow0  = wid * 32;
  const int schunk = (lane & 7) ^ (lane >> 3);
  const unsigned short* gA = A  + (m0 + srow0 + (lane >> 3)) * E_DIM + schunk * 8;
  const unsigned short* gB = Wz + (n0 + srow0 + (lane >> 3)) * E_DIM + schunk * 8;

#define STAGE(buf, k0) do { \
    _Pragma("unroll") \
    for (int i_ = 0; i_ < 4; ++i_) { \
      gload16(gA + (size_t)(i_ * 8) * E_DIM + (k0), &sA[buf][(srow0 + i_ * 8) * 64]); \
      gload16(gB + (size_t)(i_ * 8) * E_DIM + (k0), &sB[buf][(srow0 + i_ * 8) * 64]); \
    } } while (0)

  f32x4_t acc[4][4];
  #pragma unroll
  for (int i = 0; i < 4; ++i)
    #pragma unroll
    for (int j = 0; j < 4; ++j)
      acc[i][j] = (f32x4_t){0.f, 0.f, 0.f, 0.f};

  STAGE(0, 0);
  int cur = 0;
  const int fr = lane & 15;
  const int ck0 = lane >> 4;      // fragment k-chunk base (0..3)

  for (int kt = 0; kt < 8; ++kt) {            // 512 / 64
    __syncthreads();                          // staged tile (cur) complete & visible
    if (kt < 7) STAGE(cur ^ 1, (kt + 1) * 64);
    #pragma unroll
    for (int kk = 0; kk < 64; kk += 32) {
      const int ckb = (kk >> 3) + ck0;        // 0..7
      bf16x8_t af[4], bfv[4];
      #pragma unroll
      for (int i = 0; i < 4; ++i) {
        const int ra = wm * 64 + i * 16 + fr;
        af[i] = *(const bf16x8_t*)&sA[cur][ra * 64 + ((ckb ^ (ra & 7)) << 3)];
      }
      #pragma unroll
      for (int j = 0; j < 4; ++j) {
        const int rb = wn * 64 + j * 16 + fr;
        bfv[j] = *(const bf16x8_t*)&sB[cur][rb * 64 + ((ckb ^ (rb & 7)) << 3)];
      }
      #pragma unroll
      for (int i = 0; i < 4; ++i)
        #pragma unroll
        for (int j = 0; j < 4; ++j)
          acc[i][j] = __builtin_amdgcn_mfma_f32_16x16x32_bf16(af[i], bfv[j], acc[i][j], 0, 0, 0);
    }
    cur ^= 1;
  }
#undef STAGE

  // Epilogue: D row = (lane>>4)*4 + r, col = lane&15  (m89-verified C/D layout)
  unsigned short* Cb = (unsigned short*)Cout + (size_t)z * NTOK * E_DIM;
  float* Cf = (float*)Cout;
  #pragma unroll
  for (int i = 0; i < 4; ++i) {
    const int row = (int)m0 + wm * 64 + i * 16 + (lane >> 4) * 4;
    #pragma unroll
    for (int j = 0; j < 4; ++j) {
      const int col = (int)n0 + wn * 64 + j * 16 + fr;
      const float bv = bz[col];
      #pragma unroll
      for (int r = 0; r < 4; ++r) {
        const float val = acc[i][j][r] + bv;
        if constexpr (OUT_BF16)
          Cb[(size_t)(row + r) * E_DIM + col] = __builtin_bit_cast(unsigned short, (__bf16)val);
        else
          Cf[(size_t)(row + r) * E_DIM + col] = val;
      }
    }
  }
}

// ---------------- attention: gather projected rows, softmax over P=8, ctx (bf16) ----------------
__global__ __launch_bounds__(256)
void attn_kernel(const unsigned short* __restrict__ Qp, const unsigned short* __restrict__ Kp,
                 const unsigned short* __restrict__ Vp, const int* __restrict__ idx,
                 unsigned short* __restrict__ ctx)
{
  const int wid  = threadIdx.x >> 6;
  const int lane = threadIdx.x & 63;
  const int n = blockIdx.x * 4 + wid;
  const int b = n >> 11;
  const int h = lane >> 3;
  const int p = lane & 7;

  const int id = idx[n * 8 + p];
  const size_t krow = ((size_t)(b << 11) + id) * E_DIM + h * 64;
  const unsigned short* qb = Qp + (size_t)n * E_DIM + h * 64;

  float sc = 0.f;
  #pragma unroll
  for (int j = 0; j < 8; ++j) {
    u16x8_t qv = *(const u16x8_t*)(qb + j * 8);
    u16x8_t kv = *(const u16x8_t*)(Kp + krow + j * 8);
    #pragma unroll
    for (int e = 0; e < 8; ++e) sc += bf2f(qv[e]) * bf2f(kv[e]);
  }
  sc *= 0.125f;  // 1/sqrt(64)

  float m = sc;
  m = fmaxf(m, __shfl_xor(m, 1, 64));
  m = fmaxf(m, __shfl_xor(m, 2, 64));
  m = fmaxf(m, __shfl_xor(m, 4, 64));
  const float ex = __expf(sc - m);
  float dsum = ex;
  dsum += __shfl_xor(dsum, 1, 64);
  dsum += __shfl_xor(dsum, 2, 64);
  dsum += __shfl_xor(dsum, 4, 64);
  const float attn = ex / dsum;

  const int d0 = p * 8;
  float cacc[8];
  #pragma unroll
  for (int j = 0; j < 8; ++j) cacc[j] = 0.f;
  #pragma unroll
  for (int pp = 0; pp < 8; ++pp) {
    const float ap = __shfl(attn, (lane & 56) + pp, 64);
    const int  idp = __shfl(id,   (lane & 56) + pp, 64);
    const unsigned short* vb = Vp + ((size_t)(b << 11) + idp) * E_DIM + h * 64 + d0;
    u16x8_t vv = *(const u16x8_t*)vb;
    #pragma unroll
    for (int j = 0; j < 8; ++j) cacc[j] += ap * bf2f(vv[j]);
  }
  u16x8_t cc;
  #pragma unroll
  for (int j = 0; j < 8; ++j) cc[j] = __builtin_bit_cast(unsigned short, (__bf16)cacc[j]);
  *(u16x8_t*)(ctx + (size_t)n * E_DIM + h * 64 + d0) = cc;
}

extern "C" void kernel_launch(void* const* d_in, const int* in_sizes, int n_in,
                              void* d_out, int out_size, void* d_ws, size_t ws_size,
                              hipStream_t stream) {
  const float* q        = (const float*)d_in[0];
  const float* k        = (const float*)d_in[1];
  const float* v        = (const float*)d_in[2];
  const float* offset_w = (const float*)d_in[3];
  const float* offset_b = (const float*)d_in[4];
  const float* in_proj_w = (const float*)d_in[5];
  const float* in_proj_b = (const float*)d_in[6];
  const float* out_w    = (const float*)d_in[7];
  const float* out_b    = (const float*)d_in[8];

  char* ws = (char*)d_ws;
  // ws layout (u16 elements):
  // Qbf | Kbf | Vbf | Wb(786432) | OWb(262144) | Qp | Kp | Vp | idx(int)
  unsigned short* Qbf = (unsigned short*)ws;
  unsigned short* Kbf = Qbf + (size_t)NTOK * E_DIM;
  unsigned short* Vbf = Kbf + (size_t)NTOK * E_DIM;
  unsigned short* Wb  = Vbf + (size_t)NTOK * E_DIM;
  unsigned short* OWb = Wb + (size_t)3 * E_DIM * E_DIM;
  unsigned short* Qp  = OWb + (size_t)E_DIM * E_DIM;
  unsigned short* Kp  = Qp + (size_t)NTOK * E_DIM;
  unsigned short* Vp  = Kp + (size_t)NTOK * E_DIM;
  int* idxb = (int*)(Vp + (size_t)NTOK * E_DIM);
  unsigned short* ctxb = Qbf;   // alias: Qbf dead after qkv GEMM

  prepass_kernel<<<QBLK + CVTBLK, 256, 0, stream>>>(q, k, v, in_proj_w, out_w, offset_w,
                                                    offset_b, idxb, Qbf, Kbf, Vbf, Wb, OWb);
  gemm_kernel<1><<<dim3(NTOK / 128, E_DIM / 128, 3), 256, 0, stream>>>(
      Qbf, Kbf, Vbf, Wb, in_proj_b, (void*)Qp);
  attn_kernel<<<NTOK / 4, 256, 0, stream>>>(Qp, Kp, Vp, idxb, ctxb);
  gemm_kernel<0><<<dim3(NTOK / 128, E_DIM / 128, 1), 256, 0, stream>>>(
      ctxb, ctxb, ctxb, OWb, out_b, d_out);
}